// Round 7
// baseline (593.222 us; speedup 1.0000x reference)
//
#include <hip/hip_runtime.h>
#include <hip/hip_bf16.h>

// ---------------------------------------------------------------------------
// RelationalNetwork: N=32, C=24, H=W=14, O=196, HD=128, GH=256, AS=28
// pairs[n,i,j] = [feats[n,j](26), feats[n,i](26), code[n](128)]  (D_IN=180)
// h1 = relu(AJ'[n,j] + BI[n,i])        AJ' has CC (code-term) + gb0 folded in
// h  = relu(h@gw{1,2,3}+gb)            fused, bf16 MFMA 32x32x16, LDS-resident
// relations[n] = sum over 196^2 pairs  -> head MLP (fp32, tiny)
//
// Round 7: barrier-convoy attack. Correct per-CU MFMA model: r6 matrix pipe
// only 34% busy; ~40% of wall was barrier lockstep (7 barriers) + latency.
// (a) LDS ping-pong hA/hB (ROWS=64, 64 KiB): layer reads one buf, epilogue
//     writes the other -> NO barrier between MFMA and epilogue; 3 barriers.
// (b) Operand swap (mfma(W,h,acc)) for layers 1-2: same fragments, C comes
//     out transposed (reg->W-col, lane->h-row) -> epilogue = 8 packed b32
//     stores/tile (adjacent cols in one dword) instead of 16 b16.
//     Layer 3 unswapped so column-sum stays lane-local.
// (c) Wave tile 64x32 (2m x 1n): acc=32 AGPR, 4-deep W prefetch, ~105 regs
//     total, safely under the (512,4)=128 cap (r3/r4 spill lesson).
// ---------------------------------------------------------------------------

typedef __attribute__((ext_vector_type(8))) short short8;
typedef __attribute__((ext_vector_type(16))) float f32x16;

#define NIMG 32
#define O 196
#define PAIRS 38416
#define GH 256
#define AS 28
#define ROWS 64
#define CHUNKS 601          // 600*64 + 16 = 38416 (tail chunk: 16 valid rows)

#define SWZ(row) ((((row) & 7) << 4) ^ (((row) & 8) << 2))

static __device__ __forceinline__ unsigned short f2bf(float f) {
    __hip_bfloat16 h = __float2bfloat16(f);
    return *reinterpret_cast<unsigned short*>(&h);
}

// ---- setup kernel B: CC[n,g] = code[n] @ gw0[52:180] + gb0 -----------------
__global__ void k_cc(const float* __restrict__ code, const float* __restrict__ gw0,
                     const float* __restrict__ gb0, float* __restrict__ CC) {
    const int n = blockIdx.x, g = threadIdx.x;
    __shared__ float cs[128];
    if (g < 128) cs[g] = code[n * 128 + g];
    __syncthreads();
    float acc = gb0[g];
    for (int k = 0; k < 128; ++k) acc = fmaf(cs[k], gw0[(52 + k) * GH + g], acc);
    CC[n * GH + g] = acc;
}

// ---- setup kernel A: AJ'[n,p,g] (includes CC), BI[n,p,g] -------------------
__global__ void k_ajbi(const float* __restrict__ x, const float* __restrict__ gw0,
                       const float* __restrict__ CC,
                       float* __restrict__ AJ, float* __restrict__ BI) {
    const int np = blockIdx.x;            // n*196 + p
    const int n = np / O, p = np - n * O;
    const int g = threadIdx.x;
    __shared__ float fs[26];
    if (g < 24)       fs[g]  = x[(n * 24 + g) * O + p];
    else if (g == 24) fs[24] = -7.0f + (float)(p / 14) * (14.0f / 13.0f);
    else if (g == 25) fs[25] = -7.0f + (float)(p % 14) * (14.0f / 13.0f);
    __syncthreads();
    float aj = CC[n * GH + g], bi = 0.f;
#pragma unroll
    for (int c = 0; c < 26; ++c) {
        const float f = fs[c];
        aj = fmaf(f, gw0[c * GH + g], aj);
        bi = fmaf(f, gw0[(26 + c) * GH + g], bi);
    }
    AJ[np * GH + g] = aj;
    BI[np * GH + g] = bi;
}

// ---- setup kernel C: pack gw1/2/3 into 32x32x16 B-fragment layout ----------
// elem offset = L*65536 + nt*8192 + ks*512 + lane*8 + e
// value = W[ks*16 + (lane>>5)*8 + e][nt*32 + (lane&31)]
// (this layout serves as EITHER operand: as B-frag for W, or as A-frag for
//  W^T under the operand swap — same element placement either way)
__global__ void k_pack(const float* __restrict__ gw1, const float* __restrict__ gw2,
                       const float* __restrict__ gw3, unsigned short* __restrict__ pW) {
    const int idx = blockIdx.x * 256 + threadIdx.x;     // 3*65536 total
    const int L = idx >> 16;
    const int rem = idx & 0xFFFF;
    const int e = rem & 7;
    const int lane = (rem >> 3) & 63;
    const int ks = (rem >> 9) & 15;
    const int nt = rem >> 13;                            // 0..7 (column 32-slice)
    const int k = ks * 16 + ((lane >> 5) << 3) + e;
    const int col = nt * 32 + (lane & 31);
    const float* W = (L == 0) ? gw1 : (L == 1) ? gw2 : gw3;
    pW[idx] = f2bf(W[k * GH + col]);
}

// ---- main fused kernel: h1 build + 3 GEMM layers + sum-pool ----------------
__global__ __launch_bounds__(512, 4) void k_main(
    const float* __restrict__ AJ, const float* __restrict__ BI,
    const unsigned short* __restrict__ pW,
    const float* __restrict__ gb1, const float* __restrict__ gb2,
    const float* __restrict__ gb3, float* __restrict__ rel) {
    // two 64x256 bf16 buffers, XOR-swizzled byte ^= SWZ(row). 2 x 32 KiB.
    __shared__ __attribute__((aligned(16))) unsigned short hA[ROWS * GH];
    __shared__ __attribute__((aligned(16))) unsigned short hB[ROWS * GH];

    const int blk = blockIdx.x;           // n*601 + chunk
    const int n = blk / CHUNKS;
    const int chunk = blk - n * CHUNKS;
    const int row_base = chunk * ROWS;
    const int t = threadIdx.x;
    const int wave = t >> 6;              // 0..7 (= N-slice, cols wave*32..+31)
    const int lane = t & 63;
    const int l31 = lane & 31;
    const int hi = lane >> 5;
    const int l15 = lane & 15;
    const bool tail = (chunk == CHUNKS - 1);

    // ---- phase 0: h1 = relu(AJ'[j] + BI[i]) -> hA (bf16, swizzled) ----
    {
        const int i0 = row_base / O;
        const int j00 = row_base - i0 * O;
        const int i1 = min(i0 + 1, O - 1);
        const float4 bi0 = *(const float4*)&BI[(n * O + i0) * GH + lane * 4];
        const float4 bi1 = *(const float4*)&BI[(n * O + i1) * GH + lane * 4];
#pragma unroll
        for (int e = 0; e < 8; ++e) {
            const int r = wave + e * 8;
            const int jj = j00 + r;                 // one wrap max
            const bool wrap = (jj >= O);
            const int j = wrap ? jj - O : jj;       // tail garbage rows; masked later
            const float4 aj = *(const float4*)&AJ[(n * O + j) * GH + lane * 4];
            const float4 bi = wrap ? bi1 : bi0;
            const unsigned int lo = (unsigned)f2bf(fmaxf(aj.x + bi.x, 0.f)) |
                                    ((unsigned)f2bf(fmaxf(aj.y + bi.y, 0.f)) << 16);
            const unsigned int hh = (unsigned)f2bf(fmaxf(aj.z + bi.z, 0.f)) |
                                    ((unsigned)f2bf(fmaxf(aj.w + bi.w, 0.f)) << 16);
            const int byteoff = r * 512 + ((lane * 8) ^ SWZ(r));
            uint2 dd; dd.x = lo; dd.y = hh;
            *(uint2*)((char*)hA + byteoff) = dd;
        }
    }
    __syncthreads();

    const int X = SWZ(l15);               // == SWZ(row&15) for all our rows
    const int hi16 = hi << 4;
    const int arow = l31 * 512;           // h-frag row byte base (tile0)

    // K-loop: 16 steps, 4-deep W prefetch. swapped: acc += W * h (C transposed)
    auto kloop = [&](const unsigned short* bufR, const short8* wp,
                     f32x16& a0, f32x16& a1, bool swapped) {
        short8 wa = wp[lane], wb = wp[64 + lane], wc = wp[128 + lane], wd = wp[192 + lane];
        const char* hb = (const char*)bufR + arow;
#pragma unroll
        for (int ks = 0; ks < 16; ++ks) {
            const short8 W = (ks & 3) == 0 ? wa : (ks & 3) == 1 ? wb
                           : (ks & 3) == 2 ? wc : wd;
            const int off = (ks * 32 + hi16) ^ X;
            const short8 h0 = *(const short8*)(hb + off);
            const short8 h1 = *(const short8*)(hb + off + 16384);   // +32 rows
            if (swapped) {
                a0 = __builtin_amdgcn_mfma_f32_32x32x16_bf16(W, h0, a0, 0, 0, 0);
                a1 = __builtin_amdgcn_mfma_f32_32x32x16_bf16(W, h1, a1, 0, 0, 0);
            } else {
                a0 = __builtin_amdgcn_mfma_f32_32x32x16_bf16(h0, W, a0, 0, 0, 0);
                a1 = __builtin_amdgcn_mfma_f32_32x32x16_bf16(h1, W, a1, 0, 0, 0);
            }
            if (ks < 12) {
                const short8 nw = wp[(ks + 4) * 64 + lane];
                if ((ks & 3) == 0) wa = nw; else if ((ks & 3) == 1) wb = nw;
                else if ((ks & 3) == 2) wc = nw; else wd = nw;
            }
        }
    };

    // swapped epilogue: C'[reg->W-col, lane->h-row]; adjacent-col pairs packed
    // into one b32 store. Writes the OTHER buffer (no barrier needed before).
    auto epi = [&](const f32x16& a0, const f32x16& a1, const float* gb,
                   unsigned short* bufW) {
        const float4 b40 = *(const float4*)&gb[wave * 32 + 0  + 4 * hi];
        const float4 b41 = *(const float4*)&gb[wave * 32 + 8  + 4 * hi];
        const float4 b42 = *(const float4*)&gb[wave * 32 + 16 + 4 * hi];
        const float4 b43 = *(const float4*)&gb[wave * 32 + 24 + 4 * hi];
        const float bias[16] = {b40.x, b40.y, b40.z, b40.w, b41.x, b41.y, b41.z, b41.w,
                                b42.x, b42.y, b42.z, b42.w, b43.x, b43.y, b43.z, b43.w};
        char* w0 = (char*)bufW + l31 * 512;
#pragma unroll
        for (int rp = 0; rp < 8; ++rp) {
            const int r0 = rp * 2;
            const float ba = bias[(r0 >> 2) * 4 + (r0 & 3)];
            const float bb = bias[(r0 >> 2) * 4 + (r0 & 3) + 1];
            const int cw = (r0 & 3) + 8 * (r0 >> 2);           // col within slice (-4hi)
            const int cb = (wave * 64 + cw * 2 + hi * 8) ^ X;  // swizzled col byte
            const unsigned p0 = (unsigned)f2bf(fmaxf(a0[r0] + ba, 0.f)) |
                                ((unsigned)f2bf(fmaxf(a0[r0 + 1] + bb, 0.f)) << 16);
            const unsigned p1 = (unsigned)f2bf(fmaxf(a1[r0] + ba, 0.f)) |
                                ((unsigned)f2bf(fmaxf(a1[r0 + 1] + bb, 0.f)) << 16);
            *(unsigned*)(w0 + cb) = p0;
            *(unsigned*)(w0 + 16384 + cb) = p1;
        }
    };

    const f32x16 z = {0.f,0.f,0.f,0.f,0.f,0.f,0.f,0.f,0.f,0.f,0.f,0.f,0.f,0.f,0.f,0.f};
    const short8* wpb = (const short8*)pW + wave * 1024;   // wave's 32-col W slice

    // ---- layer 1: read hA, epi -> hB ----
    f32x16 acc0 = z, acc1 = z;
    kloop(hA, wpb, acc0, acc1, true);
    epi(acc0, acc1, gb1, hB);
    __syncthreads();

    // ---- layer 2: read hB, epi -> hA ----
    acc0 = z; acc1 = z;
    kloop(hB, wpb + 8192, acc0, acc1, true);
    epi(acc0, acc1, gb2, hA);
    __syncthreads();

    // ---- layer 3 (unswapped): read hA, bias+relu+column-sum -> atomic ----
    acc0 = z; acc1 = z;
    kloop(hA, wpb + 16384, acc0, acc1, false);
    {
        const float bias = gb3[wave * 32 + l31];
        float s = 0.f;
        if (!tail) {
#pragma unroll
            for (int r = 0; r < 16; ++r)
                s += fmaxf(acc0[r] + bias, 0.f) + fmaxf(acc1[r] + bias, 0.f);
        } else {
            // valid rows 0..15 -> tile0 regs 0..7 (rows (r&3)+8*(r>>2)+4hi < 16)
#pragma unroll
            for (int r = 0; r < 8; ++r)
                s += fmaxf(acc0[r] + bias, 0.f);
        }
        s += __shfl_xor(s, 32);
        if (hi == 0) atomicAdd(&rel[n * GH + wave * 32 + l31], s);
    }
}

// ---- head MLP (fp32, tiny): relations -> logits ----------------------------
__global__ void k_fmlp(const float* __restrict__ rel,
                       const float* __restrict__ fw0, const float* __restrict__ fb0,
                       const float* __restrict__ fw1, const float* __restrict__ fb1,
                       const float* __restrict__ fw2, const float* __restrict__ fb2,
                       float* __restrict__ out) {
    __shared__ float b0[GH], b1[GH];
    const int n = blockIdx.x, g = threadIdx.x;
    b0[g] = rel[n * GH + g];
    __syncthreads();
    float a = fb0[g];
    for (int k = 0; k < GH; ++k) a = fmaf(b0[k], fw0[k * GH + g], a);
    b1[g] = fmaxf(a, 0.f);
    __syncthreads();
    float c = fb1[g];
    for (int k = 0; k < GH; ++k) c = fmaf(b1[k], fw1[k * GH + g], c);
    b0[g] = fmaxf(c, 0.f);
    __syncthreads();
    if (g < AS) {
        float o = fb2[g];
        for (int k = 0; k < GH; ++k) o = fmaf(b0[k], fw2[k * AS + g], o);
        out[n * AS + g] = o;
    }
}

// ---------------------------------------------------------------------------
extern "C" void kernel_launch(void* const* d_in, const int* in_sizes, int n_in,
                              void* d_out, int out_size, void* d_ws, size_t ws_size,
                              hipStream_t stream) {
    const float* x    = (const float*)d_in[0];
    const float* code = (const float*)d_in[1];
    const float* gw0  = (const float*)d_in[2];
    const float* gb0  = (const float*)d_in[3];
    const float* gw1  = (const float*)d_in[4];
    const float* gb1  = (const float*)d_in[5];
    const float* gw2  = (const float*)d_in[6];
    const float* gb2  = (const float*)d_in[7];
    const float* gw3  = (const float*)d_in[8];
    const float* gb3  = (const float*)d_in[9];
    const float* fw0  = (const float*)d_in[10];
    const float* fb0  = (const float*)d_in[11];
    const float* fw1  = (const float*)d_in[12];
    const float* fb1  = (const float*)d_in[13];
    const float* fw2  = (const float*)d_in[14];
    const float* fb2  = (const float*)d_in[15];
    float* out = (float*)d_out;

    char* ws = (char*)d_ws;
    // workspace layout (16B aligned)
    float*          AJ  = (float*)(ws + 0);                 // 32*196*256*4 = 6,422,528
    float*          BI  = (float*)(ws + 6422528);           // 6,422,528
    float*          CC  = (float*)(ws + 12845056);          // 32,768
    float*          rel = (float*)(ws + 12877824);          // 32,768
    unsigned short* pW  = (unsigned short*)(ws + 12910592); // 3*65536*2 = 393,216

    hipMemsetAsync(rel, 0, NIMG * GH * sizeof(float), stream);
    k_cc<<<NIMG, 256, 0, stream>>>(code, gw0, gb0, CC);
    k_ajbi<<<NIMG * O, 256, 0, stream>>>(x, gw0, CC, AJ, BI);
    k_pack<<<768, 256, 0, stream>>>(gw1, gw2, gw3, pW);
    k_main<<<NIMG * CHUNKS, 512, 0, stream>>>(AJ, BI, pW, gb1, gb2, gb3, rel);
    k_fmlp<<<NIMG, 256, 0, stream>>>(rel, fw0, fb0, fw1, fb1, fw2, fb2, out);
}